// Round 15
// baseline (386.804 us; speedup 1.0000x reference)
//
#include <hip/hip_runtime.h>
#include <hip/hip_bf16.h>
#include <math.h>

#define EMBED 1024
#define FFN   4096
#define NW    8
#define MTOT  32768   // 16*2048

#define BM 256
#define BN 256
#define BK 64
#define NT (FFN / BK)   // 64 K-tiles

#define STRIP 128
#define KPT   8

typedef __attribute__((ext_vector_type(8))) short          short8v;
typedef __attribute__((ext_vector_type(8))) unsigned short ushort8v;
typedef __attribute__((ext_vector_type(4))) float          f32x4;

typedef __attribute__((address_space(1))) void gvoid_t;
typedef __attribute__((address_space(3))) void svoid_t;

#define VMCNT(n)  asm volatile("s_waitcnt vmcnt(" #n ")" ::: "memory")
#define BAR()     __builtin_amdgcn_s_barrier()

static __device__ __forceinline__ unsigned short bf16bits(float f) {
    __hip_bfloat16 h = __float2bfloat16(f);
    return *reinterpret_cast<unsigned short*>(&h);
}

// ---------------- W2 f32 -> bf16 (once, into ws) ----------------
__global__ __launch_bounds__(256) void cvtW2_kernel(const float* __restrict__ W2,
                                                    __hip_bfloat16* __restrict__ Bw) {
    const long i0 = ((long)blockIdx.x * 256 + threadIdx.x) * 8;
    const float4 a = *(const float4*)(W2 + i0);
    const float4 b = *(const float4*)(W2 + i0 + 4);
    float fs[8] = {a.x, a.y, a.z, a.w, b.x, b.y, b.z, b.w};
    ushort8v v;
#pragma unroll
    for (int t = 0; t < 8; ++t) v[t] = bf16bits(fs[t]);
    *reinterpret_cast<ushort8v*>(Bw + i0) = v;
}

// ---------------- producer: h[m,k] = relu(b1[k] + qz[m,:]·W1[k,:]) ----------------
__global__ __launch_bounds__(256) void hprod2_kernel(
    const float* __restrict__ x, const float* __restrict__ theta,
    const float* __restrict__ W1, const float* __restrict__ b1,
    __hip_bfloat16* __restrict__ h, int m0)
{
    __shared__ float qz_lds[STRIP][NW];
    const int tid   = threadIdx.x;
    const int khalf = blockIdx.x & 1;
    const int strip = blockIdx.x >> 1;
    const int k0    = khalf * 2048 + tid * KPT;

    float w1r[KPT][NW];
    float b1r[KPT];
#pragma unroll
    for (int i = 0; i < KPT; ++i) {
        const float4 a = *(const float4*)(W1 + (long)(k0 + i) * NW);
        const float4 b = *(const float4*)(W1 + (long)(k0 + i) * NW + 4);
        w1r[i][0] = a.x; w1r[i][1] = a.y; w1r[i][2] = a.z; w1r[i][3] = a.w;
        w1r[i][4] = b.x; w1r[i][5] = b.y; w1r[i][6] = b.z; w1r[i][7] = b.w;
        b1r[i] = b1[k0 + i];
    }

    if (tid < STRIP) {
        const long m = (long)m0 + (long)strip * STRIP + tid;
        const float* xr = x + m * (long)EMBED;
#pragma unroll
        for (int w = 0; w < NW; ++w)
            qz_lds[tid][w] = cosf(xr[w]) * cosf(theta[w]);
    }
    __syncthreads();

    __hip_bfloat16* hp = h + ((long)strip * STRIP) * FFN + k0;
    for (int r = 0; r < STRIP; ++r) {
        float q[NW];
#pragma unroll
        for (int w = 0; w < NW; ++w) q[w] = qz_lds[r][w];
        ushort8v hv;
#pragma unroll
        for (int i = 0; i < KPT; ++i) {
            float acc = b1r[i];
#pragma unroll
            for (int w = 0; w < NW; ++w) acc = fmaf(q[w], w1r[i][w], acc);
            hv[i] = bf16bits(fmaxf(acc, 0.0f));
        }
        *reinterpret_cast<ushort8v*>(hp + (long)r * FFN) = hv;
    }
}

// ---------------- GEMM v15: v14 ledger + CORRECTED stage-halves ----------------
// out[M,1024] = h[M,4096] @ W2bf[1024,4096]^T + b2
// R14 NaN root cause: stage-half h covered rows h*128..h*128+127, but P1's
// READ_A6(t,0) touches rows {0-63} AND {128-191} (wr=0/1) -> wr=1 waves read
// staged-half-1 LDS before its drain (end-P2). Fix: redefine stage-halves to
// EXACTLY the rows each read-phase consumes:
//   A stage-half h = rows {h*64..h*64+63} u {h*64+128..h*64+191}
//     (two gloads at row offsets h*64 and h*64+128)
//     READ_A6(t,a) rows wr*128+a*64+{0..63} -> subset of stage-half a. OK
//   B stage-half h = rows with bit5==h = {h*32 + 64k + 0..31, k=0..3}
//     wave->row base brow=(wid>>1)*64+(wid&1)*8+(lane>>3); gloads at +h*32,
//     +h*32+16.  READ_B6(t,b) rows wc*64+b*32+{0..31} -> subset of half b. OK
// All offsets are multiples of 8 -> row&7 preserved -> proven swizzle intact.
// Wait ledger (per-thread, 8 loads/iter, verified incl. prologue+tail):
//   end-P1 vmcnt(2): drains B(t)h1 (staged P3(t-1), age 3 phases)
//   end-P2 vmcnt(4): drains A(t)h1 (staged P4(t-1), age 3); tail t=NT-1: vmcnt(0)
//   end-P4 vmcnt(4): drains A(t+1)h0+B(t+1)h0 (staged P2(t), age 2.5)
// Overwrite safety: every staged region's previous occupant last read >=4
// barriers earlier. 16x16x32 MFMA (2-way LDS aliasing = free; 32x32 was
// 4-way, R13). No sched_barrier (R8 null). setprio on MFMA clusters (T5).
__global__ __launch_bounds__(512, 2) void gemm15_kernel(
    const __hip_bfloat16* __restrict__ A,   // [rows][FFN] chunk-local h
    const __hip_bfloat16* __restrict__ Bw,  // [EMBED][FFN] W2 bf16
    const float* __restrict__ b2,
    float* __restrict__ out, long m0, int nPm)
{
    __shared__ __align__(16) __hip_bfloat16 As[2][BM * BK];  // 64 KB
    __shared__ __align__(16) __hip_bfloat16 Bs[2][BN * BK];  // 64 KB

    const int tid = threadIdx.x, wid = tid >> 6, lane = tid & 63;
    const int l15 = lane & 15, l4 = lane >> 4;
    const int wr = wid >> 2, wc = wid & 3;           // 2M x 4N wave grid

    // XCD map: all 4 pn of a pm co-resident on one XCD; pm chunked per XCD.
    const int xcd = blockIdx.x & 7, kb = blockIdx.x >> 3;
    const int pn  = kb & 3;
    const int pm  = xcd * (nPm >> 3) + (kb >> 2);

    // staging lane geometry; source col pre-XORed by row&7 (swizzle pair)
    const int srow  = tid >> 3;                          // wid*8 + (lane>>3)
    const int colsw = ((tid & 7) ^ (srow & 7)) * 8;
    // B wave->row remap so each stage-half is the bit5==h row set
    const int brow  = ((wid >> 1) << 6) + ((wid & 1) << 3) + (lane >> 3);

    const __hip_bfloat16* Ag = A  + (long)(pm * BM + srow) * FFN + colsw;
    const __hip_bfloat16* Bg = Bw + (long)(pn * BN + brow) * FFN + colsw;

    f32x4 acc[8][4];
#pragma unroll
    for (int i = 0; i < 8; ++i)
#pragma unroll
        for (int j = 0; j < 4; ++j) acc[i][j] = (f32x4){0.f, 0.f, 0.f, 0.f};

    // A stage-half h: rows h*64+{0..63} (gload0) and h*64+128+{0..63} (gload1)
#define STAGE_A6(t, h) do {                                                     \
    const __hip_bfloat16* _g = Ag + (long)((h) * 64) * FFN + (t) * BK;          \
    __builtin_amdgcn_global_load_lds((gvoid_t*)_g,                              \
        (svoid_t*)(&As[(t) & 1][((h) * 64 + wid * 8) * BK]), 16, 0, 0);         \
    __builtin_amdgcn_global_load_lds((gvoid_t*)(_g + (long)128 * FFN),          \
        (svoid_t*)(&As[(t) & 1][((h) * 64 + 128 + wid * 8) * BK]), 16, 0, 0);   \
} while (0)

    // B stage-half h: rows h*32 + {brow rows} (gload0) and +16 (gload1)
#define STAGE_B6(t, h) do {                                                     \
    const __hip_bfloat16* _g = Bg + (long)((h) * 32) * FFN + (t) * BK;          \
    const int _r = (h) * 32 + ((wid >> 1) << 6) + ((wid & 1) << 3);             \
    __builtin_amdgcn_global_load_lds((gvoid_t*)_g,                              \
        (svoid_t*)(&Bs[(t) & 1][_r * BK]), 16, 0, 0);                           \
    __builtin_amdgcn_global_load_lds((gvoid_t*)(_g + (long)16 * FFN),           \
        (svoid_t*)(&Bs[(t) & 1][(_r + 16) * BK]), 16, 0, 0);                    \
} while (0)

    const int rx = (l15 & 7) << 3;   // read-side elem XOR; row&7 == l15&7

    short8v aF[4][2];       // current A half-frags (overwritten at P3)
    short8v bF[2][2][2];    // [b-half][ni][kk]

#define READ_A6(t, a) do { _Pragma("unroll")                                    \
    for (int mi = 0; mi < 4; ++mi) {                                            \
        const int row = wr * 128 + (a) * 64 + mi * 16 + l15;                    \
        _Pragma("unroll") for (int kk = 0; kk < 2; ++kk)                        \
            aF[mi][kk] = *reinterpret_cast<const short8v*>(                     \
                &As[(t) & 1][row * BK + ((kk * 32 + l4 * 8) ^ rx)]);            \
    } } while (0)

#define READ_B6(t, b) do { _Pragma("unroll")                                    \
    for (int ni = 0; ni < 2; ++ni) {                                            \
        const int row = wc * 64 + (b) * 32 + ni * 16 + l15;                     \
        _Pragma("unroll") for (int kk = 0; kk < 2; ++kk)                        \
            bF[b][ni][kk] = *reinterpret_cast<const short8v*>(                  \
                &Bs[(t) & 1][row * BK + ((kk * 32 + l4 * 8) ^ rx)]);            \
    } } while (0)

#define MFMA_Q(aa, bb) do { _Pragma("unroll")                                   \
    for (int mi = 0; mi < 4; ++mi) _Pragma("unroll")                            \
    for (int ni = 0; ni < 2; ++ni) _Pragma("unroll")                            \
    for (int kk = 0; kk < 2; ++kk)                                              \
        acc[(aa) * 4 + mi][(bb) * 2 + ni] =                                     \
            __builtin_amdgcn_mfma_f32_16x16x32_bf16(                            \
                aF[mi][kk], bF[bb][ni][kk], acc[(aa) * 4 + mi][(bb) * 2 + ni],  \
                0, 0, 0);                                                       \
} while (0)

    // prologue: tile0 in steady-state FIFO order; vmcnt(4) leaves h1 pair in flight
    STAGE_A6(0, 0); STAGE_B6(0, 0); STAGE_B6(0, 1); STAGE_A6(0, 1);
    VMCNT(4); BAR();

    for (int t = 0; t < NT; ++t) {
        // ---- P1: read A(t)h0 + B(t)h0; MFMA q(0,0) ----
        READ_A6(t, 0); READ_B6(t, 0);
        BAR();
        __builtin_amdgcn_s_setprio(1); MFMA_Q(0, 0); __builtin_amdgcn_s_setprio(0);
        VMCNT(2);                       // drains B(t)h1 (staged P3(t-1), age 3)
        BAR();
        // ---- P2: stage A(t+1)h0 + B(t+1)h0; read B(t)h1; MFMA q(0,1) ----
        if (t + 1 < NT) { STAGE_A6(t + 1, 0); STAGE_B6(t + 1, 0); }
        READ_B6(t, 1);
        BAR();
        __builtin_amdgcn_s_setprio(1); MFMA_Q(0, 1); __builtin_amdgcn_s_setprio(0);
        if (t + 1 < NT) { VMCNT(4); }   // drains A(t)h1 (staged P4(t-1), age 3)
        else            { VMCNT(0); }   // tail: nothing staged this iter
        BAR();
        // ---- P3: stage B(t+1)h1; read A(t)h1; MFMA q(1,1) ----
        if (t + 1 < NT) STAGE_B6(t + 1, 1);
        READ_A6(t, 1);
        BAR();
        __builtin_amdgcn_s_setprio(1); MFMA_Q(1, 1); __builtin_amdgcn_s_setprio(0);
        BAR();
        // ---- P4: stage A(t+1)h1; MFMA q(1,0) ----
        if (t + 1 < NT) STAGE_A6(t + 1, 1);
        BAR();
        __builtin_amdgcn_s_setprio(1); MFMA_Q(1, 0); __builtin_amdgcn_s_setprio(0);
        VMCNT(4);                       // drains A/B(t+1)h0 (staged P2(t), age 2.5)
        BAR();
    }

#undef STAGE_A6
#undef STAGE_B6
#undef READ_A6
#undef READ_B6
#undef MFMA_Q

    // epilogue: + b2, f32 store. C/D: col=lane&15, row=(lane>>4)*4+reg
    const int gn0 = pn * BN + wc * 64;
    float bias[4];
#pragma unroll
    for (int ni = 0; ni < 4; ++ni) bias[ni] = b2[gn0 + ni * 16 + l15];
    const long gm0 = m0 + (long)pm * BM + wr * 128;
#pragma unroll
    for (int mi = 0; mi < 8; ++mi)
#pragma unroll
        for (int ni = 0; ni < 4; ++ni)
#pragma unroll
            for (int j = 0; j < 4; ++j) {
                const long row = gm0 + mi * 16 + l4 * 4 + j;
                out[row * EMBED + gn0 + ni * 16 + l15] = acc[mi][ni][j] + bias[ni];
            }
}

extern "C" void kernel_launch(void* const* d_in, const int* in_sizes, int n_in,
                              void* d_out, int out_size, void* d_ws, size_t ws_size,
                              hipStream_t stream)
{
    const float* x     = (const float*)d_in[0];
    const float* theta = (const float*)d_in[1];
    const float* W1    = (const float*)d_in[2];
    const float* b1    = (const float*)d_in[3];
    const float* W2    = (const float*)d_in[4];
    const float* b2    = (const float*)d_in[5];
    float* out = (float*)d_out;

    const size_t w2b = (size_t)EMBED * FFN * 2;          // 8.4 MB bf16 W2
    __hip_bfloat16* Bw = (__hip_bfloat16*)d_ws;
    __hip_bfloat16* h  = (__hip_bfloat16*)((char*)d_ws + w2b);
    const size_t avail = ws_size > w2b ? ws_size - w2b : 0;

    // chunk = 16384 rows: h-chunk (134MB) L3-resident between hprod and gemm.
    long chunk = (long)((avail / ((size_t)FFN * 2)) & ~2047UL);
    if (chunk > 16384) chunk = 16384;
    if (chunk < 2048)  chunk = 2048;

    cvtW2_kernel<<<(EMBED * FFN) / 2048, 256, 0, stream>>>(W2, Bw);

    for (long m0 = 0; m0 < MTOT; m0 += chunk) {
        const long rows = (MTOT - m0 < chunk) ? (MTOT - m0) : chunk;
        hprod2_kernel<<<(int)((rows / STRIP) * 2), 256, 0, stream>>>(
            x, theta, W1, b1, h, (int)m0);
        const int nPm = (int)(rows / BM);                 // multiple of 8
        gemm15_kernel<<<nPm * 4, 512, 0, stream>>>(h, Bw, b2, out, m0, nPm);
    }
}

// Round 16
// 359.091 us; speedup vs baseline: 1.0772x; 1.0772x over previous
//
#include <hip/hip_runtime.h>
#include <hip/hip_bf16.h>
#include <math.h>

#define EMBED 1024
#define FFN   4096
#define NW    8
#define MTOT  32768   // 16*2048

#define BM 128
#define BN 128
#define BK 64
#define NT (FFN / BK)   // 64 K-tiles

#define STRIP 128
#define KPT   8

typedef __attribute__((ext_vector_type(8))) short          short8v;
typedef __attribute__((ext_vector_type(8))) unsigned short ushort8v;
typedef __attribute__((ext_vector_type(4))) float          f32x4;

typedef __attribute__((address_space(1))) void gvoid_t;
typedef __attribute__((address_space(3))) void svoid_t;

static __device__ __forceinline__ unsigned short bf16bits(float f) {
    __hip_bfloat16 h = __float2bfloat16(f);
    return *reinterpret_cast<unsigned short*>(&h);
}

// ---------------- W2 f32 -> bf16 (once, into ws) ----------------
__global__ __launch_bounds__(256) void cvtW2_kernel(const float* __restrict__ W2,
                                                    __hip_bfloat16* __restrict__ Bw) {
    const long i0 = ((long)blockIdx.x * 256 + threadIdx.x) * 8;
    const float4 a = *(const float4*)(W2 + i0);
    const float4 b = *(const float4*)(W2 + i0 + 4);
    float fs[8] = {a.x, a.y, a.z, a.w, b.x, b.y, b.z, b.w};
    ushort8v v;
#pragma unroll
    for (int t = 0; t < 8; ++t) v[t] = bf16bits(fs[t]);
    *reinterpret_cast<ushort8v*>(Bw + i0) = v;
}

// ---------------- producer: h[m,k] = relu(b1[k] + qz[m,:]·W1[k,:]) ----------------
// W1 slice in registers, rows stream, qz broadcast from LDS. Write-BW-bound
// (~50us for 268MB = 5.4 TB/s, at the floor).
__global__ __launch_bounds__(256) void hprod2_kernel(
    const float* __restrict__ x, const float* __restrict__ theta,
    const float* __restrict__ W1, const float* __restrict__ b1,
    __hip_bfloat16* __restrict__ h, int m0)
{
    __shared__ float qz_lds[STRIP][NW];
    const int tid   = threadIdx.x;
    const int khalf = blockIdx.x & 1;
    const int strip = blockIdx.x >> 1;
    const int k0    = khalf * 2048 + tid * KPT;

    float w1r[KPT][NW];
    float b1r[KPT];
#pragma unroll
    for (int i = 0; i < KPT; ++i) {
        const float4 a = *(const float4*)(W1 + (long)(k0 + i) * NW);
        const float4 b = *(const float4*)(W1 + (long)(k0 + i) * NW + 4);
        w1r[i][0] = a.x; w1r[i][1] = a.y; w1r[i][2] = a.z; w1r[i][3] = a.w;
        w1r[i][4] = b.x; w1r[i][5] = b.y; w1r[i][6] = b.z; w1r[i][7] = b.w;
        b1r[i] = b1[k0 + i];
    }

    if (tid < STRIP) {
        const long m = (long)m0 + (long)strip * STRIP + tid;
        const float* xr = x + m * (long)EMBED;
#pragma unroll
        for (int w = 0; w < NW; ++w)
            qz_lds[tid][w] = cosf(xr[w]) * cosf(theta[w]);
    }
    __syncthreads();

    __hip_bfloat16* hp = h + ((long)strip * STRIP) * FFN + k0;
    for (int r = 0; r < STRIP; ++r) {
        float q[NW];
#pragma unroll
        for (int w = 0; w < NW; ++w) q[w] = qz_lds[r][w];
        ushort8v hv;
#pragma unroll
        for (int i = 0; i < KPT; ++i) {
            float acc = b1r[i];
#pragma unroll
            for (int w = 0; w < NW; ++w) acc = fmaf(q[w], w1r[i][w], acc);
            hv[i] = bf16bits(fmaxf(acc, 0.0f));
        }
        *reinterpret_cast<ushort8v*>(hp + (long)r * FFN) = hv;
    }
}

// ---------------- GEMM (R12, measured best: 306us ~ 898 TF) ----------------
// out[M,1024] = h[M,4096] @ W2bf[1024,4096]^T + b2
// Session-final structure, each element evidence-backed:
//  * 128x128 tile, BK=64, 4 waves (2x2), 16x16x32 MFMA: 16-row frag groups
//    alias LDS banks only 2-way = free (m136); 32x32 was 4-way (-18%, R13).
//  * kk-major compute + narrow frag liveness: 56 VGPR + 64 AGPR = 120 < 128
//    occupancy cliff (m69) -> ~3 independent blocks/CU.
//  * __launch_bounds__(256,4) pins the allocator under the cliff (R12: the
//    single biggest win of the session, 415->306us vs phase schedules).
//  * plain __syncthreads loop: independent co-resident blocks overlap
//    read/MFMA/drain intervals (m114); every explicit phase/vmcnt schedule
//    tried (R5-R8, R14, R15) measured SLOWER at this shape.
//  * zero-conflict swizzle pair: global source col pre-XORed by row&7,
//    ds_read XORs the same -> SQ_LDS_BANK_CONFLICT == 0 (R4-proven).
//  * XCD map: per pm, all 8 pn consecutive on one XCD -> A panel L2-hot.
__global__ __launch_bounds__(256, 4) void gemm12_kernel(
    const __hip_bfloat16* __restrict__ A,   // [rows][FFN] chunk-local h
    const __hip_bfloat16* __restrict__ Bw,  // [EMBED][FFN] W2 bf16
    const float* __restrict__ b2,
    float* __restrict__ out, long m0, int nPm)
{
    __shared__ __align__(16) __hip_bfloat16 As[BM * BK];  // 16 KB
    __shared__ __align__(16) __hip_bfloat16 Bs[BN * BK];  // 16 KB

    const int tid = threadIdx.x, wid = tid >> 6, lane = tid & 63;
    const int l15 = lane & 15, l4 = lane >> 4;
    const int wr = wid >> 1, wc = wid & 1;          // 2M x 2N wave grid

    // XCD map: bid = xcd + 8*j; per pm, 8 pn back-to-back on one XCD.
    const int xcd = blockIdx.x & 7, j = blockIdx.x >> 3;
    const int pn  = j & 7;
    const int pm  = xcd * (nPm >> 3) + (j >> 3);

    // staging: 8 threads/row (8x16B=128B row); 4 sweeps of 32 rows.
    const int srow  = tid >> 3;                     // 0..31
    const int colsw = ((tid & 7) ^ (srow & 7)) * 8;

    const __hip_bfloat16* Ag = A  + (long)(pm * BM + srow) * FFN + colsw;
    const __hip_bfloat16* Bg = Bw + (long)(pn * BN + srow) * FFN + colsw;

    f32x4 acc[4][4];
#pragma unroll
    for (int i = 0; i < 4; ++i)
#pragma unroll
        for (int jj = 0; jj < 4; ++jj) acc[i][jj] = (f32x4){0.f, 0.f, 0.f, 0.f};

    const int rx = (l15 & 7) << 3;   // read-side elem XOR; row&7 == l15&7

    for (int t = 0; t < NT; ++t) {
        __syncthreads();   // previous tile's reads complete before overwrite
#pragma unroll
        for (int s = 0; s < 4; ++s) {
            __builtin_amdgcn_global_load_lds(
                (gvoid_t*)(Ag + (long)(s * 32) * FFN + t * BK),
                (svoid_t*)(&As[(s * 32 + wid * 8) * BK]), 16, 0, 0);
            __builtin_amdgcn_global_load_lds(
                (gvoid_t*)(Bg + (long)(s * 32) * FFN + t * BK),
                (svoid_t*)(&Bs[(s * 32 + wid * 8) * BK]), 16, 0, 0);
        }
        __syncthreads();   // tile resident (vmcnt0 drain; sibling blocks hide)

        // kk-major: narrow liveness (bv[4]=16 + av=4 regs live, not 64)
#pragma unroll
        for (int kk = 0; kk < 2; ++kk) {
            short8v bv[4];
#pragma unroll
            for (int ni = 0; ni < 4; ++ni) {
                const int row = wc * 64 + ni * 16 + l15;
                bv[ni] = *reinterpret_cast<const short8v*>(
                    &Bs[row * BK + ((kk * 32 + l4 * 8) ^ rx)]);
            }
#pragma unroll
            for (int mi = 0; mi < 4; ++mi) {
                const int row = wr * 64 + mi * 16 + l15;
                const short8v av = *reinterpret_cast<const short8v*>(
                    &As[row * BK + ((kk * 32 + l4 * 8) ^ rx)]);
#pragma unroll
                for (int ni = 0; ni < 4; ++ni)
                    acc[mi][ni] = __builtin_amdgcn_mfma_f32_16x16x32_bf16(
                        av, bv[ni], acc[mi][ni], 0, 0, 0);
            }
        }
    }

    // epilogue: + b2, f32 store. C/D: col=lane&15, row=(lane>>4)*4+reg
    const int gn0 = pn * BN + wc * 64;
    float bias[4];
#pragma unroll
    for (int ni = 0; ni < 4; ++ni) bias[ni] = b2[gn0 + ni * 16 + l15];
    const long gm0 = m0 + (long)pm * BM + wr * 64;
#pragma unroll
    for (int mi = 0; mi < 4; ++mi)
#pragma unroll
        for (int ni = 0; ni < 4; ++ni)
#pragma unroll
            for (int jj = 0; jj < 4; ++jj) {
                const long row = gm0 + mi * 16 + l4 * 4 + jj;
                out[row * EMBED + gn0 + ni * 16 + l15] = acc[mi][ni][jj] + bias[ni];
            }
}

extern "C" void kernel_launch(void* const* d_in, const int* in_sizes, int n_in,
                              void* d_out, int out_size, void* d_ws, size_t ws_size,
                              hipStream_t stream)
{
    const float* x     = (const float*)d_in[0];
    const float* theta = (const float*)d_in[1];
    const float* W1    = (const float*)d_in[2];
    const float* b1    = (const float*)d_in[3];
    const float* W2    = (const float*)d_in[4];
    const float* b2    = (const float*)d_in[5];
    float* out = (float*)d_out;

    const size_t w2b = (size_t)EMBED * FFN * 2;          // 8.4 MB bf16 W2
    __hip_bfloat16* Bw = (__hip_bfloat16*)d_ws;
    __hip_bfloat16* h  = (__hip_bfloat16*)((char*)d_ws + w2b);
    const size_t avail = ws_size > w2b ? ws_size - w2b : 0;

    long chunk = (long)((avail / ((size_t)FFN * 2)) & ~2047UL); // mult of 2048 rows
    if (chunk > MTOT) chunk = MTOT;
    if (chunk < 2048) chunk = 2048;

    cvtW2_kernel<<<(EMBED * FFN) / 2048, 256, 0, stream>>>(W2, Bw);

    for (long m0 = 0; m0 < MTOT; m0 += chunk) {
        const long rows = (MTOT - m0 < chunk) ? (MTOT - m0) : chunk;
        hprod2_kernel<<<(int)((rows / STRIP) * 2), 256, 0, stream>>>(
            x, theta, W1, b1, h, (int)m0);
        const int nPm = (int)(rows / BM);                 // multiple of 16
        gemm12_kernel<<<nPm * 8, 256, 0, stream>>>(h, Bw, b2, out, m0, nPm);
    }
}